// Round 5
// baseline (564.557 us; speedup 1.0000x reference)
//
#include <hip/hip_runtime.h>

typedef unsigned short u16;
typedef unsigned int   u32;
typedef unsigned long long u64;
typedef float f2 __attribute__((ext_vector_type(2)));

#define CIN  20
#define DIN  32
#define BB   4
#define HH   384
#define WW   384
#define HW   147456
#define BHW  589824
#define EPSF 1e-5f
#define GUARD  65536      // streams with <=49152B 4-step overrun
#define UGUARD 131072     // u stream: 4-step overrun 98304 < 128K

__device__ __forceinline__ float bflo(u32 u) {
    union { u32 v; float f; } x; x.v = u << 16; return x.f;
}
__device__ __forceinline__ float bfhi(u32 u) {
    union { u32 v; float f; } x; x.v = u & 0xffff0000u; return x.f;
}
__device__ __forceinline__ float bf2f(u16 h) {
    union { u32 v; float f; } x; x.v = ((u32)h) << 16; return x.f;
}
__device__ __forceinline__ u16 f2bf(float f) {
    union { float f; u32 u; } v; v.f = f;
    u32 u = v.u;
    return (u16)((u + 0x7FFFu + ((u >> 16) & 1u)) >> 16);
}
__device__ __forceinline__ float silu_f(float a) {
    return a / (1.f + __expf(-a));
}
__device__ __forceinline__ float softplus_f(float z) {
    return (z > 15.f) ? z : __logf(1.f + __expf(z));
}

// ---------------- K0: fold merge+out weights ----------------
__global__ void k_prep(const float* __restrict__ ow, const float* __restrict__ mw,
                       const float* __restrict__ mg, const float* __restrict__ mb,
                       const float* __restrict__ ob,
                       float* __restrict__ Wt, float* __restrict__ rsum,
                       float* __restrict__ c0)
{
    __shared__ float mdot[DIN];
    int t = threadIdx.x; // 128 threads
    if (t < DIN) {
        float s = 0.f;
        for (int k = 0; k < 128; ++k) s += mw[t*128 + k] * mb[k];
        mdot[t] = s;
    }
    {
        int k = t;
        for (int o = 0; o < CIN; ++o) {
            float s = 0.f;
            for (int d = 0; d < DIN; ++d) s += ow[o*DIN + d] * mw[d*128 + k];
            Wt[k*CIN + o] = s * mg[k];
        }
    }
    __syncthreads();
    if (t < CIN) {
        float rs = 0.f;
        for (int k = 0; k < 128; ++k) rs += Wt[k*CIN + t];
        rsum[t] = rs;
        float c = ob[t];
        for (int d = 0; d < DIN; ++d) c += ow[t*DIN + d] * mdot[d];
        c0[t] = c;
    }
}

// ---------------- K1: layernorm(C=20) + inproj(20->32) + silu ----------------
__global__ __launch_bounds__(256) void k_lnproj(
    const float* __restrict__ x, const float* __restrict__ ng,
    const float* __restrict__ nb, const float* __restrict__ ipw,
    u16* __restrict__ h1)
{
    __shared__ float w_s[DIN*CIN];
    __shared__ float g_s[CIN], b_s[CIN];
    for (int i = threadIdx.x; i < DIN*CIN; i += 256) w_s[i] = ipw[i];
    if (threadIdx.x < CIN) { g_s[threadIdx.x] = ng[threadIdx.x]; b_s[threadIdx.x] = nb[threadIdx.x]; }
    __syncthreads();

    int p = blockIdx.x*256 + threadIdx.x;
    int b = p / HW, rem = p % HW;
    float v[CIN];
    float m = 0.f;
    #pragma unroll
    for (int c = 0; c < CIN; ++c) { v[c] = x[(b*CIN + c)*HW + rem]; m += v[c]; }
    m *= (1.f/CIN);
    float var = 0.f;
    #pragma unroll
    for (int c = 0; c < CIN; ++c) { float d = v[c]-m; var += d*d; }
    var *= (1.f/CIN);
    float rstd = rsqrtf(var + EPSF);
    #pragma unroll
    for (int c = 0; c < CIN; ++c) v[c] = (v[c]-m)*rstd*g_s[c] + b_s[c];

    float o[DIN];
    #pragma unroll
    for (int j = 0; j < DIN; ++j) {
        float acc = 0.f;
        #pragma unroll
        for (int c = 0; c < CIN; ++c) acc += w_s[j*CIN + c]*v[c];
        o[j] = silu_f(acc);
    }
    u32 pk[16];
    #pragma unroll
    for (int j2 = 0; j2 < 16; ++j2)
        pk[j2] = (u32)f2bf(o[2*j2]) | ((u32)f2bf(o[2*j2+1]) << 16);
    uint4* dst = (uint4*)(h1 + (size_t)p*DIN);
    dst[0] = make_uint4(pk[0],pk[1],pk[2],pk[3]);
    dst[1] = make_uint4(pk[4],pk[5],pk[6],pk[7]);
    dst[2] = make_uint4(pk[8],pk[9],pk[10],pk[11]);
    dst[3] = make_uint4(pk[12],pk[13],pk[14],pk[15]);
}

// ---------------- K2: depthwise 3x3 conv + bias + silu ----------------
__global__ __launch_bounds__(256) void k_conv(
    const u16* __restrict__ h1, const float* __restrict__ cw,
    const float* __restrict__ cb, u16* __restrict__ h2)
{
    __shared__ float w_s[9*DIN];
    __shared__ float b_s[DIN];
    for (int i = threadIdx.x; i < 9*DIN; i += 256) w_s[i] = cw[i];
    if (threadIdx.x < DIN) b_s[threadIdx.x] = cb[threadIdx.x];
    __syncthreads();

    int tid = blockIdx.x*256 + threadIdx.x;
    int p = tid >> 2, g = tid & 3;
    int b = p / HW, rem = p % HW;
    int yy0 = rem / WW, xx0 = rem % WW;

    float acc[8];
    #pragma unroll
    for (int i = 0; i < 8; ++i) acc[i] = b_s[g*8 + i];

    #pragma unroll
    for (int dy = -1; dy <= 1; ++dy) {
        int yy = yy0 + dy;
        #pragma unroll
        for (int dx = -1; dx <= 1; ++dx) {
            int xc = xx0 + dx;
            if (yy >= 0 && yy < HH && xc >= 0 && xc < WW) {
                uint4 q = *(const uint4*)(h1 + ((size_t)(b*HW + yy*WW + xc)*DIN + g*8));
                int k = (dy+1)*3 + (dx+1);
                const float* wp = &w_s[k*DIN + g*8];
                acc[0] += wp[0]*bflo(q.x);  acc[1] += wp[1]*bfhi(q.x);
                acc[2] += wp[2]*bflo(q.y);  acc[3] += wp[3]*bfhi(q.y);
                acc[4] += wp[4]*bflo(q.z);  acc[5] += wp[5]*bfhi(q.z);
                acc[6] += wp[6]*bflo(q.w);  acc[7] += wp[7]*bfhi(q.w);
            }
        }
    }
    u32 pk[4];
    #pragma unroll
    for (int i2 = 0; i2 < 4; ++i2) {
        float a = silu_f(acc[2*i2]);
        float c = silu_f(acc[2*i2+1]);
        pk[i2] = (u32)f2bf(a) | ((u32)f2bf(c) << 16);
    }
    *(uint4*)(h2 + ((size_t)p*DIN + g*8)) = make_uint4(pk[0],pk[1],pk[2],pk[3]);
}

// ---------------- K3: xdbl -> dl array (8B/rec) + BC array (32B/rec) ----------------
__global__ __launch_bounds__(256) void k_proj(
    const u16* __restrict__ h2, const float* __restrict__ xw,
    u16* __restrict__ dlA, u16* __restrict__ bcA)
{
    __shared__ float xw_s[4*CIN*DIN];
    for (int i = threadIdx.x; i < 4*CIN*DIN; i += 256) xw_s[i] = xw[i];
    __syncthreads();

    int p = blockIdx.x*256 + threadIdx.x;
    float u[DIN];
    const uint4* src = (const uint4*)(h2 + (size_t)p*DIN);
    #pragma unroll
    for (int q4 = 0; q4 < 4; ++q4) {
        uint4 v = src[q4];
        u[q4*8+0]=bflo(v.x); u[q4*8+1]=bfhi(v.x);
        u[q4*8+2]=bflo(v.y); u[q4*8+3]=bfhi(v.y);
        u[q4*8+4]=bflo(v.z); u[q4*8+5]=bfhi(v.z);
        u[q4*8+6]=bflo(v.w); u[q4*8+7]=bfhi(v.w);
    }
    #pragma unroll 1
    for (int dir = 0; dir < 4; ++dir) {
        float xd[CIN];
        #pragma unroll
        for (int j = 0; j < CIN; ++j) xd[j] = 0.f;
        #pragma unroll
        for (int d4 = 0; d4 < 8; ++d4) {
            float u0 = u[d4*4], u1 = u[d4*4+1], u2 = u[d4*4+2], u3 = u[d4*4+3];
            #pragma unroll
            for (int j = 0; j < CIN; ++j) {
                float4 w4 = *(const float4*)&xw_s[(dir*CIN + j)*DIN + d4*4];
                xd[j] += w4.x*u0 + w4.y*u1 + w4.z*u2 + w4.w*u3;
            }
        }
        u32 pk[10];
        #pragma unroll
        for (int i = 0; i < 10; ++i)
            pk[i] = (u32)f2bf(xd[2*i]) | ((u32)f2bf(xd[2*i+1]) << 16);
        *(uint2*)(dlA + (size_t)(dir*BHW + p)*4) = make_uint2(pk[0], pk[1]);
        uint4* bcd = (uint4*)(bcA + (size_t)(dir*BHW + p)*16);
        bcd[0] = make_uint4(pk[2], pk[3], pk[4], pk[5]);   // B0..B7
        bcd[1] = make_uint4(pk[6], pk[7], pk[8], pk[9]);   // C0..C7
    }
}

// ---------------- K4: 4-direction selective scan ----------------
// lane = d (32 ch), 2 sequences per wave, 8 states/lane as 4x float2.
// Software-pipelined (prep for t+1 overlaps FMA work of t), prefetch depth 4.
// NEW: per-step y goes to a per-sequence LDS tile (lgkmcnt domain); a flush
// every 32 steps emits coalesced dwordx4 global stores. This keeps scattered
// 2B stores out of the vmcnt FIFO, whose in-order retirement otherwise makes
// every ring-slot s_waitcnt drain slow stores (the suspected ~60% stall).
__global__ __launch_bounds__(256) void k_scan(
    const char* __restrict__ h2b,   // u data at +UGUARD
    const char* __restrict__ dlb_,  // dl data at +GUARD (8B records)
    const char* __restrict__ bcb_,  // (B,C) data at +GUARD (32B records)
    const float* __restrict__ Alog, const float* __restrict__ Dp,
    const float* __restrict__ dwm,  const float* __restrict__ dbv,
    char* __restrict__ y4b)         // planar (dir, pixel, 32) bf16
{
    // [8 sequences per block][32 steps][32 ch] bf16 = 16KB
    __shared__ u16 ybuf[8*32*32];

    int tid  = blockIdx.x*256 + threadIdx.x;
    int wv   = tid >> 6, lane = tid & 63;
    int half = lane >> 5, d = lane & 31;
    int dir  = wv / 768;                 // uniform per wave
    int s    = (wv % 768)*2 + half;
    int b    = s / 384, r = s % 384;
    int slot = ((threadIdx.x >> 6) << 1) + half;     // 0..7 per block

    int p0, stp;
    if (dir == 0)      { p0 = b*HW + r*WW;           stp = 1;  }
    else if (dir == 1) { p0 = b*HW + r*WW + (WW-1);  stp = -1; }
    else if (dir == 2) { p0 = b*HW + r;              stp = WW; }
    else               { p0 = b*HW + (HH-1)*WW + r;  stp = -WW;}

    float Av[8];
    bool okl = true;
    #pragma unroll
    for (int j = 0; j < 8; ++j) {
        float e = __expf(Alog[(dir*DIN + d)*8 + j]);
        Av[j] = -e;
        okl = okl && (__builtin_fabsf(e - (float)(j+1)) < 2e-3f);
    }
    bool fast = (__ballot(okl) == ~0ull);

    float Dd  = Dp[dir*DIN + d];
    float dw0 = dwm[(dir*DIN + d)*4 + 0], dw1 = dwm[(dir*DIN + d)*4 + 1];
    float dw2 = dwm[(dir*DIN + d)*4 + 2], dw3 = dwm[(dir*DIN + d)*4 + 3];
    float dbc = dbv[dir*DIN + d];

    u32 uo = UGUARD + (u32)((p0*DIN + d)*2);           int su = stp*DIN*2;
    u32 c1 = GUARD + (u32)((dir*BHW + p0)*8);          int s1 = stp*8;
    u32 c2 = GUARD + (u32)((dir*BHW + p0)*32);         int s2 = stp*32;

    int sy   = stp*64;                                 // y byte stride per step
    u32 yb0  = (u32)((dir*BHW + p0)*64);               // window base (d-agnostic)
    int ci   = d & 3;                                  // 16B chunk within a row
    int jrow = d >> 2;                                 // row handled in flush

    u16 ub[4]; uint2 dlr[4]; uint4 B4[4], C4[4];
    u32 fu = uo, f1 = c1, f2o = c2;

    auto fetch = [&](int sl) {
        ub[sl]  = *(const u16*)(h2b + fu);
        dlr[sl] = *(const uint2*)(dlb_ + f1);
        B4[sl]  = *(const uint4*)(bcb_ + f2o);
        C4[sl]  = *(const uint4*)(bcb_ + f2o + 16);
        fu += (u32)su; f1 += (u32)s1; f2o += (u32)s2;
    };

    #pragma unroll
    for (int i = 0; i < 4; ++i) fetch(i);

    // per-step LDS write address (elements); +32 per step, reset each window
    int la0 = slot*1024 + d;

    auto flush = [&]() {
        #pragma unroll
        for (int i = 0; i < 4; ++i) {
            int j = i*8 + jrow;
            uint4 v = *(const uint4*)&ybuf[slot*1024 + j*32 + ci*8];
            *(uint4*)(y4b + (yb0 + (u32)(j*sy)) + ci*16) = v;
        }
        yb0 += (u32)(sy*32);
    };

    f2 h0 = {0.f,0.f}, h1v = {0.f,0.f}, h2v = {0.f,0.f}, h3 = {0.f,0.f};

    if (fast) {
        f2 a01, a23, a45, a67;
        f2 Bq0, Bq1, Bq2, Bq3;
        f2 Cp0, Cp1, Cp2, Cp3;
        float ydc;

        auto prep = [&](int sl) {
            float uu = bf2f(ub[sl]);
            uint2 dl = dlr[sl];
            uint4 Bv = B4[sl], Cv = C4[sl];
            float z = dbc + dw0*bflo(dl.x) + dw1*bfhi(dl.x)
                          + dw2*bflo(dl.y) + dw3*bfhi(dl.y);
            z = fminf(z, 80.f);
            float ez = __expf(z);
            float w  = 1.f + ez;
            float rr = __builtin_amdgcn_rcpf(w);   // = exp(-dt)
            float dt = __logf(w);                  // softplus(z); parallel with rcp
            float r2 = rr*rr;
            f2 rr2 = {r2, r2};
            f2 t01 = {rr, r2};
            a01 = t01;
            a23 = t01*rr2;
            a45 = a23*rr2;
            a67 = a45*rr2;
            float dtu = dt*uu;
            f2 du2 = {dtu, dtu};
            f2 Bp0 = { bflo(Bv.x), bfhi(Bv.x) }, Bp1 = { bflo(Bv.y), bfhi(Bv.y) };
            f2 Bp2 = { bflo(Bv.z), bfhi(Bv.z) }, Bp3 = { bflo(Bv.w), bfhi(Bv.w) };
            Bq0 = du2*Bp0; Bq1 = du2*Bp1; Bq2 = du2*Bp2; Bq3 = du2*Bp3;
            f2 c0 = { bflo(Cv.x), bfhi(Cv.x) }, c1v = { bflo(Cv.y), bfhi(Cv.y) };
            f2 c2v = { bflo(Cv.z), bfhi(Cv.z) }, c3 = { bflo(Cv.w), bfhi(Cv.w) };
            Cp0 = c0; Cp1 = c1v; Cp2 = c2v; Cp3 = c3;
            ydc = Dd*uu;
        };

        prep(0);

        for (int t0 = 0; t0 < 384; t0 += 32) {
            int la = la0;
            #pragma unroll 4
            for (int tm = 0; tm < 32; ++tm) {
                int sl = tm & 3;
                fetch(sl);

                h0  = __builtin_elementwise_fma(a01, h0,  Bq0);
                h1v = __builtin_elementwise_fma(a23, h1v, Bq1);
                h2v = __builtin_elementwise_fma(a45, h2v, Bq2);
                h3  = __builtin_elementwise_fma(a67, h3,  Bq3);

                f2 yv = Cp0*h0;
                yv = __builtin_elementwise_fma(Cp1, h1v, yv);
                yv = __builtin_elementwise_fma(Cp2, h2v, yv);
                yv = __builtin_elementwise_fma(Cp3, h3,  yv);
                float y = yv.x + yv.y + ydc;

                prep((tm+1) & 3);

                ybuf[la] = f2bf(y);
                la += 32;
            }
            flush();
        }
    } else {
        f2 A2[4];
        #pragma unroll
        for (int j = 0; j < 4; ++j) { A2[j].x = Av[2*j]; A2[j].y = Av[2*j+1]; }
        for (int t0 = 0; t0 < 384; t0 += 32) {
            int la = la0;
            #pragma unroll 4
            for (int tm = 0; tm < 32; ++tm) {
                int sl = tm & 3;
                float uu = bf2f(ub[sl]);
                uint2 dl = dlr[sl];
                uint4 Bv = B4[sl], Cv = C4[sl];
                fetch(sl);

                float z = dbc + dw0*bflo(dl.x) + dw1*bfhi(dl.x)
                              + dw2*bflo(dl.y) + dw3*bfhi(dl.y);
                float dt = softplus_f(z);
                f2 dt2 = {dt, dt};
                f2 e0 = dt2*A2[0], e1 = dt2*A2[1], e2 = dt2*A2[2], e3 = dt2*A2[3];
                f2 a01 = { __expf(e0.x), __expf(e0.y) };
                f2 a23 = { __expf(e1.x), __expf(e1.y) };
                f2 a45 = { __expf(e2.x), __expf(e2.y) };
                f2 a67 = { __expf(e3.x), __expf(e3.y) };

                float dtu = dt*uu;
                f2 du2 = {dtu, dtu};
                f2 Bp0 = { bflo(Bv.x), bfhi(Bv.x) }, Bp1 = { bflo(Bv.y), bfhi(Bv.y) };
                f2 Bp2 = { bflo(Bv.z), bfhi(Bv.z) }, Bp3 = { bflo(Bv.w), bfhi(Bv.w) };
                f2 Cp0 = { bflo(Cv.x), bfhi(Cv.x) }, Cp1 = { bflo(Cv.y), bfhi(Cv.y) };
                f2 Cp2 = { bflo(Cv.z), bfhi(Cv.z) }, Cp3 = { bflo(Cv.w), bfhi(Cv.w) };

                h0  = __builtin_elementwise_fma(a01, h0,  du2*Bp0);
                h1v = __builtin_elementwise_fma(a23, h1v, du2*Bp1);
                h2v = __builtin_elementwise_fma(a45, h2v, du2*Bp2);
                h3  = __builtin_elementwise_fma(a67, h3,  du2*Bp3);

                f2 yv = Cp0*h0;
                yv = __builtin_elementwise_fma(Cp1, h1v, yv);
                yv = __builtin_elementwise_fma(Cp2, h2v, yv);
                yv = __builtin_elementwise_fma(Cp3, h3,  yv);

                float y = yv.x + yv.y + Dd*uu;
                ybuf[la] = f2bf(y);
                la += 32;
            }
            flush();
        }
    }
}

// ---------------- K5: LN(128) + folded 128->20 + NCHW transpose ----------------
__global__ __launch_bounds__(256) void k_merge(
    const u16* __restrict__ y4, const float* __restrict__ Wt,
    const float* __restrict__ rsum, const float* __restrict__ c0,
    float* __restrict__ out)
{
    __shared__ float Wt_s[128*CIN];
    __shared__ float rs_s[CIN], c0_s[CIN];
    for (int i = threadIdx.x; i < 128*CIN; i += 256) Wt_s[i] = Wt[i];
    if (threadIdx.x < CIN) { rs_s[threadIdx.x] = rsum[threadIdx.x]; c0_s[threadIdx.x] = c0[threadIdx.x]; }
    __syncthreads();

    int p = blockIdx.x*256 + threadIdx.x;
    int b = p / HW, rem = p % HW;

    float s1 = 0.f, s2 = 0.f;
    float acc[CIN];
    #pragma unroll
    for (int o = 0; o < CIN; ++o) acc[o] = 0.f;

    #pragma unroll 1
    for (int dirk = 0; dirk < 4; ++dirk) {
        const uint4* src = (const uint4*)(y4 + ((size_t)dirk*BHW + p)*32);
        #pragma unroll
        for (int q4 = 0; q4 < 4; ++q4) {
            uint4 v = src[q4];
            u32 w[4] = {v.x, v.y, v.z, v.w};
            #pragma unroll
            for (int i = 0; i < 4; ++i) {
                int k = dirk*32 + q4*8 + i*2;
                float a = bflo(w[i]); float c = bfhi(w[i]);
                s1 += a + c; s2 += a*a + c*c;
                const float4* w0 = (const float4*)&Wt_s[k*CIN];
                const float4* w1 = (const float4*)&Wt_s[(k+1)*CIN];
                #pragma unroll
                for (int o4 = 0; o4 < 5; ++o4) {
                    float4 x0 = w0[o4], x1 = w1[o4];
                    acc[o4*4+0] += x0.x*a + x1.x*c;
                    acc[o4*4+1] += x0.y*a + x1.y*c;
                    acc[o4*4+2] += x0.z*a + x1.z*c;
                    acc[o4*4+3] += x0.w*a + x1.w*c;
                }
            }
        }
    }
    float m = s1*(1.f/128.f);
    float var = s2*(1.f/128.f) - m*m;
    float rstd = rsqrtf(var + EPSF);
    #pragma unroll
    for (int o = 0; o < CIN; ++o) {
        float res = rstd*(acc[o] - m*rs_s[o]) + c0_s[o];
        out[(b*CIN + o)*HW + rem] = res;
    }
}

extern "C" void kernel_launch(void* const* d_in, const int* in_sizes, int n_in,
                              void* d_out, int out_size, void* d_ws, size_t ws_size,
                              hipStream_t stream)
{
    const float* x    = (const float*)d_in[0];
    const float* ng   = (const float*)d_in[1];
    const float* nb   = (const float*)d_in[2];
    const float* ipw  = (const float*)d_in[3];
    const float* cw   = (const float*)d_in[4];
    const float* cb   = (const float*)d_in[5];
    const float* xw   = (const float*)d_in[6];
    const float* dwm  = (const float*)d_in[7];
    const float* dbv  = (const float*)d_in[8];
    const float* Alog = (const float*)d_in[9];
    const float* Dpv  = (const float*)d_in[10];
    const float* mg   = (const float*)d_in[11];
    const float* mb   = (const float*)d_in[12];
    const float* mw   = (const float*)d_in[13];
    const float* ow   = (const float*)d_in[14];
    const float* ob   = (const float*)d_in[15];
    float* out = (float*)d_out;

    const size_t y4_bytes = (size_t)4*BHW*DIN*2;     // 150,994,944 (planar)
    const size_t dl_bytes = (size_t)4*BHW*8;         //  18,874,368
    const size_t bc_bytes = (size_t)4*BHW*32;        //  75,497,472
    const size_t wt_bytes = (size_t)(128*CIN + 64)*4;

    char* ws = (char*)d_ws;
    u16* y4 = (u16*)ws;
    u16* h1 = y4;                                    // alias: h1 dead before y4 written

    size_t dl_pos = y4_bytes + GUARD;
    size_t bc_pos = dl_pos + dl_bytes + GUARD;
    size_t wt_pos = bc_pos + bc_bytes + GUARD;
    size_t need   = wt_pos + wt_bytes + GUARD;       // ~245.6 MB (proven budget; ws < 321MB per R4)

    if (ws_size < need) {
        hipMemsetAsync(d_out, 0x7F, (size_t)out_size*4, stream);  // diagnosable sentinel
        return;
    }

    // h2 (u after conv) lives inside d_out with UGUARD front guard (128K for
    // 4-deep prefetch overrun of the vertical-scan u stream: 4*24576 = 96K).
    char* h2base = (char*)d_out;                     // data at +UGUARD
    u16*  h2 = (u16*)(h2base + UGUARD);              // 128K + 37.75MB + 9.3MB tail < 47.19 MB

    u16* dlA = (u16*)(ws + dl_pos);
    u16* bcA = (u16*)(ws + bc_pos);
    float* Wt   = (float*)(ws + wt_pos);
    float* rsum = Wt + 128*CIN;
    float* c0   = rsum + 32;

    k_prep  <<<1, 128, 0, stream>>>(ow, mw, mg, mb, ob, Wt, rsum, c0);
    k_lnproj<<<BHW/256, 256, 0, stream>>>(x, ng, nb, ipw, h1);
    k_conv  <<<BHW*4/256, 256, 0, stream>>>(h1, cw, cb, h2);
    k_proj  <<<BHW/256, 256, 0, stream>>>(h2, xw, dlA, bcA);
    k_scan  <<<768, 256, 0, stream>>>(
        h2base, (const char*)(ws + dl_pos - GUARD), (const char*)(ws + bc_pos - GUARD),
        Alog, Dpv, dwm, dbv, (char*)y4);
    k_merge <<<BHW/256, 256, 0, stream>>>(y4, Wt, rsum, c0, out);
}

// Round 6
// 478.421 us; speedup vs baseline: 1.1800x; 1.1800x over previous
//
#include <hip/hip_runtime.h>

typedef unsigned short u16;
typedef unsigned int   u32;
typedef unsigned long long u64;
typedef float f2 __attribute__((ext_vector_type(2)));

#define CIN  20
#define DIN  32
#define BB   4
#define HH   384
#define WW   384
#define HW   147456
#define BHW  589824
#define EPSF 1e-5f
#define GUARD  65536      // streams with <=49152B 4-step overrun
#define UGUARD 131072     // u stream: 4-step overrun 98304 < 128K

__device__ __forceinline__ float bflo(u32 u) {
    union { u32 v; float f; } x; x.v = u << 16; return x.f;
}
__device__ __forceinline__ float bfhi(u32 u) {
    union { u32 v; float f; } x; x.v = u & 0xffff0000u; return x.f;
}
__device__ __forceinline__ float bf2f(u16 h) {
    union { u32 v; float f; } x; x.v = ((u32)h) << 16; return x.f;
}
__device__ __forceinline__ u16 f2bf(float f) {
    union { float f; u32 u; } v; v.f = f;
    u32 u = v.u;
    return (u16)((u + 0x7FFFu + ((u >> 16) & 1u)) >> 16);
}
__device__ __forceinline__ float silu_f(float a) {
    return a / (1.f + __expf(-a));
}
__device__ __forceinline__ float softplus_f(float z) {
    return (z > 15.f) ? z : __logf(1.f + __expf(z));
}

// ---------------- K0: fold merge+out weights ----------------
__global__ void k_prep(const float* __restrict__ ow, const float* __restrict__ mw,
                       const float* __restrict__ mg, const float* __restrict__ mb,
                       const float* __restrict__ ob,
                       float* __restrict__ Wt, float* __restrict__ rsum,
                       float* __restrict__ c0)
{
    __shared__ float mdot[DIN];
    int t = threadIdx.x; // 128 threads
    if (t < DIN) {
        float s = 0.f;
        for (int k = 0; k < 128; ++k) s += mw[t*128 + k] * mb[k];
        mdot[t] = s;
    }
    {
        int k = t;
        for (int o = 0; o < CIN; ++o) {
            float s = 0.f;
            for (int d = 0; d < DIN; ++d) s += ow[o*DIN + d] * mw[d*128 + k];
            Wt[k*CIN + o] = s * mg[k];
        }
    }
    __syncthreads();
    if (t < CIN) {
        float rs = 0.f;
        for (int k = 0; k < 128; ++k) rs += Wt[k*CIN + t];
        rsum[t] = rs;
        float c = ob[t];
        for (int d = 0; d < DIN; ++d) c += ow[t*DIN + d] * mdot[d];
        c0[t] = c;
    }
}

// ---------------- K1: layernorm(C=20) + inproj(20->32) + silu ----------------
// pk-FMA form: outputs paired into 16 f2 accumulators; weights pre-paired in
// LDS as [c][j2] so 8 ds_read_b128 per c feed 16 pk_fma. Accumulation order
// over c identical to scalar version (bit-exact).
__global__ __launch_bounds__(256) void k_lnproj(
    const float* __restrict__ x, const float* __restrict__ ng,
    const float* __restrict__ nb, const float* __restrict__ ipw,
    u16* __restrict__ h1)
{
    __shared__ __align__(16) f2 w2_s[CIN*16];   // [c][j2] = {w[2j2][c], w[2j2+1][c]}
    __shared__ float g_s[CIN], b_s[CIN];
    for (int i = threadIdx.x; i < CIN*16; i += 256) {
        int c = i >> 4, j2 = i & 15;
        w2_s[i] = f2{ ipw[(2*j2)*CIN + c], ipw[(2*j2+1)*CIN + c] };
    }
    if (threadIdx.x < CIN) { g_s[threadIdx.x] = ng[threadIdx.x]; b_s[threadIdx.x] = nb[threadIdx.x]; }
    __syncthreads();

    int p = blockIdx.x*256 + threadIdx.x;
    int b = p / HW, rem = p % HW;
    float v[CIN];
    float m = 0.f;
    #pragma unroll
    for (int c = 0; c < CIN; ++c) { v[c] = x[(b*CIN + c)*HW + rem]; m += v[c]; }
    m *= (1.f/CIN);
    float var = 0.f;
    #pragma unroll
    for (int c = 0; c < CIN; ++c) { float d = v[c]-m; var += d*d; }
    var *= (1.f/CIN);
    float rstd = rsqrtf(var + EPSF);
    #pragma unroll
    for (int c = 0; c < CIN; ++c) v[c] = (v[c]-m)*rstd*g_s[c] + b_s[c];

    f2 o2[16];
    #pragma unroll
    for (int j2 = 0; j2 < 16; ++j2) o2[j2] = f2{0.f, 0.f};
    #pragma unroll
    for (int c = 0; c < CIN; ++c) {
        f2 vc = { v[c], v[c] };
        const float4* wr = (const float4*)&w2_s[c*16];
        #pragma unroll
        for (int jq = 0; jq < 8; ++jq) {
            float4 wp = wr[jq];
            o2[2*jq]   = __builtin_elementwise_fma(f2{wp.x, wp.y}, vc, o2[2*jq]);
            o2[2*jq+1] = __builtin_elementwise_fma(f2{wp.z, wp.w}, vc, o2[2*jq+1]);
        }
    }
    u32 pk[16];
    #pragma unroll
    for (int j2 = 0; j2 < 16; ++j2) {
        float a = silu_f(o2[j2].x);
        float c = silu_f(o2[j2].y);
        pk[j2] = (u32)f2bf(a) | ((u32)f2bf(c) << 16);
    }
    uint4* dst = (uint4*)(h1 + (size_t)p*DIN);
    dst[0] = make_uint4(pk[0],pk[1],pk[2],pk[3]);
    dst[1] = make_uint4(pk[4],pk[5],pk[6],pk[7]);
    dst[2] = make_uint4(pk[8],pk[9],pk[10],pk[11]);
    dst[3] = make_uint4(pk[12],pk[13],pk[14],pk[15]);
}

// ---------------- K2: depthwise 3x3 conv + bias + silu (pk-FMA) ----------------
__global__ __launch_bounds__(256) void k_conv(
    const u16* __restrict__ h1, const float* __restrict__ cw,
    const float* __restrict__ cb, u16* __restrict__ h2)
{
    __shared__ __align__(16) f2 w2_s[9*16];   // [k][dp] = {cw[k*32+2dp], cw[k*32+2dp+1]}
    __shared__ f2 b2_s[16];
    for (int i = threadIdx.x; i < 9*16; i += 256)
        w2_s[i] = f2{ cw[2*i], cw[2*i+1] };
    if (threadIdx.x < 16)
        b2_s[threadIdx.x] = f2{ cb[2*threadIdx.x], cb[2*threadIdx.x+1] };
    __syncthreads();

    int tid = blockIdx.x*256 + threadIdx.x;
    int p = tid >> 2, g = tid & 3;
    int b = p / HW, rem = p % HW;
    int yy0 = rem / WW, xx0 = rem % WW;

    f2 acc2[4];
    #pragma unroll
    for (int i = 0; i < 4; ++i) acc2[i] = b2_s[g*4 + i];

    #pragma unroll
    for (int dy = -1; dy <= 1; ++dy) {
        int yy = yy0 + dy;
        #pragma unroll
        for (int dx = -1; dx <= 1; ++dx) {
            int xc = xx0 + dx;
            if (yy >= 0 && yy < HH && xc >= 0 && xc < WW) {
                uint4 q = *(const uint4*)(h1 + ((size_t)(b*HW + yy*WW + xc)*DIN + g*8));
                int k = (dy+1)*3 + (dx+1);
                const float4* wp4 = (const float4*)&w2_s[k*16 + g*4];
                float4 wA = wp4[0], wB = wp4[1];
                acc2[0] = __builtin_elementwise_fma(f2{wA.x,wA.y}, f2{bflo(q.x),bfhi(q.x)}, acc2[0]);
                acc2[1] = __builtin_elementwise_fma(f2{wA.z,wA.w}, f2{bflo(q.y),bfhi(q.y)}, acc2[1]);
                acc2[2] = __builtin_elementwise_fma(f2{wB.x,wB.y}, f2{bflo(q.z),bfhi(q.z)}, acc2[2]);
                acc2[3] = __builtin_elementwise_fma(f2{wB.z,wB.w}, f2{bflo(q.w),bfhi(q.w)}, acc2[3]);
            }
        }
    }
    u32 pk[4];
    #pragma unroll
    for (int i2 = 0; i2 < 4; ++i2) {
        float a = silu_f(acc2[i2].x);
        float c = silu_f(acc2[i2].y);
        pk[i2] = (u32)f2bf(a) | ((u32)f2bf(c) << 16);
    }
    *(uint4*)(h2 + ((size_t)p*DIN + g*8)) = make_uint4(pk[0],pk[1],pk[2],pk[3]);
}

// ---------------- K3: xdbl -> dl (8B/rec) + BC (32B/rec), pk-FMA ----------------
// Outputs paired into 10 f2; weights pre-paired as [(dir*32+d)*10 + j2]
// so 5 ds_read_b128 per (dir,d) feed 10 pk_fma with broadcast u[d].
__global__ __launch_bounds__(256) void k_proj(
    const u16* __restrict__ h2, const float* __restrict__ xw,
    u16* __restrict__ dlA, u16* __restrict__ bcA)
{
    __shared__ __align__(16) f2 xw2_s[4*DIN*10];
    for (int i = threadIdx.x; i < 4*DIN*10; i += 256) {
        int dir = i / 320, r = i % 320;
        int d = r / 10, j2 = r % 10;
        xw2_s[i] = f2{ xw[(dir*CIN + 2*j2)*DIN + d],
                       xw[(dir*CIN + 2*j2 + 1)*DIN + d] };
    }
    __syncthreads();

    int p = blockIdx.x*256 + threadIdx.x;
    float u[DIN];
    const uint4* src = (const uint4*)(h2 + (size_t)p*DIN);
    #pragma unroll
    for (int q4 = 0; q4 < 4; ++q4) {
        uint4 v = src[q4];
        u[q4*8+0]=bflo(v.x); u[q4*8+1]=bfhi(v.x);
        u[q4*8+2]=bflo(v.y); u[q4*8+3]=bfhi(v.y);
        u[q4*8+4]=bflo(v.z); u[q4*8+5]=bfhi(v.z);
        u[q4*8+6]=bflo(v.w); u[q4*8+7]=bfhi(v.w);
    }
    #pragma unroll 1
    for (int dir = 0; dir < 4; ++dir) {
        f2 xd2[10];
        #pragma unroll
        for (int j2 = 0; j2 < 10; ++j2) xd2[j2] = f2{0.f, 0.f};
        #pragma unroll
        for (int d = 0; d < DIN; ++d) {
            f2 ud = { u[d], u[d] };
            const float4* wr = (const float4*)&xw2_s[(dir*DIN + d)*10];
            #pragma unroll
            for (int jq = 0; jq < 5; ++jq) {
                float4 wp = wr[jq];
                xd2[2*jq]   = __builtin_elementwise_fma(f2{wp.x, wp.y}, ud, xd2[2*jq]);
                xd2[2*jq+1] = __builtin_elementwise_fma(f2{wp.z, wp.w}, ud, xd2[2*jq+1]);
            }
        }
        u32 pk[10];
        #pragma unroll
        for (int i = 0; i < 10; ++i)
            pk[i] = (u32)f2bf(xd2[i].x) | ((u32)f2bf(xd2[i].y) << 16);
        *(uint2*)(dlA + (size_t)(dir*BHW + p)*4) = make_uint2(pk[0], pk[1]);
        uint4* bcd = (uint4*)(bcA + (size_t)(dir*BHW + p)*16);
        bcd[0] = make_uint4(pk[2], pk[3], pk[4], pk[5]);   // B0..B7
        bcd[1] = make_uint4(pk[6], pk[7], pk[8], pk[9]);   // C0..C7
    }
}

// ---------------- K4: 4-direction selective scan [R2 champion, unchanged] ----------------
// lane = d (32 ch), 2 sequences per wave, 8 states/lane as 4x float2.
// Software-pipelined (prep for t+1 overlaps FMA work of t), prefetch depth 4,
// rcp and log computed in parallel from w = 1+e^z.
__global__ __launch_bounds__(256) void k_scan(
    const char* __restrict__ h2b,   // u data at +UGUARD
    const char* __restrict__ dlb_,  // dl data at +GUARD (8B records)
    const char* __restrict__ bcb_,  // (B,C) data at +GUARD (32B records)
    const float* __restrict__ Alog, const float* __restrict__ Dp,
    const float* __restrict__ dwm,  const float* __restrict__ dbv,
    char* __restrict__ y4b)         // planar (dir, pixel, 32) bf16
{
    int tid  = blockIdx.x*256 + threadIdx.x;
    int wv   = tid >> 6, lane = tid & 63;
    int half = lane >> 5, d = lane & 31;
    int dir  = wv / 768;                 // uniform per wave
    int s    = (wv % 768)*2 + half;
    int b    = s / 384, r = s % 384;

    int p0, stp;
    if (dir == 0)      { p0 = b*HW + r*WW;           stp = 1;  }
    else if (dir == 1) { p0 = b*HW + r*WW + (WW-1);  stp = -1; }
    else if (dir == 2) { p0 = b*HW + r;              stp = WW; }
    else               { p0 = b*HW + (HH-1)*WW + r;  stp = -WW;}

    float Av[8];
    bool okl = true;
    #pragma unroll
    for (int j = 0; j < 8; ++j) {
        float e = __expf(Alog[(dir*DIN + d)*8 + j]);
        Av[j] = -e;
        okl = okl && (__builtin_fabsf(e - (float)(j+1)) < 2e-3f);
    }
    bool fast = (__ballot(okl) == ~0ull);

    float Dd  = Dp[dir*DIN + d];
    float dw0 = dwm[(dir*DIN + d)*4 + 0], dw1 = dwm[(dir*DIN + d)*4 + 1];
    float dw2 = dwm[(dir*DIN + d)*4 + 2], dw3 = dwm[(dir*DIN + d)*4 + 3];
    float dbc = dbv[dir*DIN + d];

    u32 uo = UGUARD + (u32)((p0*DIN + d)*2);           int su = stp*DIN*2;
    u32 yo = (u32)((dir*BHW + p0)*64 + d*2);           int sy = stp*64;
    u32 c1 = GUARD + (u32)((dir*BHW + p0)*8);          int s1 = stp*8;
    u32 c2 = GUARD + (u32)((dir*BHW + p0)*32);         int s2 = stp*32;

    u16 ub[4]; uint2 dlr[4]; uint4 B4[4], C4[4];
    u32 fu = uo, f1 = c1, f2o = c2;

    auto fetch = [&](int sl) {
        ub[sl]  = *(const u16*)(h2b + fu);
        dlr[sl] = *(const uint2*)(dlb_ + f1);
        B4[sl]  = *(const uint4*)(bcb_ + f2o);
        C4[sl]  = *(const uint4*)(bcb_ + f2o + 16);
        fu += (u32)su; f1 += (u32)s1; f2o += (u32)s2;
    };

    #pragma unroll
    for (int i = 0; i < 4; ++i) fetch(i);

    f2 h0 = {0.f,0.f}, h1v = {0.f,0.f}, h2v = {0.f,0.f}, h3 = {0.f,0.f};

    if (fast) {
        f2 a01, a23, a45, a67;
        f2 Bq0, Bq1, Bq2, Bq3;
        f2 Cp0, Cp1, Cp2, Cp3;
        float ydc;

        auto prep = [&](int sl) {
            float uu = bf2f(ub[sl]);
            uint2 dl = dlr[sl];
            uint4 Bv = B4[sl], Cv = C4[sl];
            float z = dbc + dw0*bflo(dl.x) + dw1*bfhi(dl.x)
                          + dw2*bflo(dl.y) + dw3*bfhi(dl.y);
            z = fminf(z, 80.f);
            float ez = __expf(z);
            float w  = 1.f + ez;
            float rr = __builtin_amdgcn_rcpf(w);   // = exp(-dt)
            float dt = __logf(w);                  // softplus(z); parallel with rcp
            float r2 = rr*rr;
            f2 rr2 = {r2, r2};
            f2 t01 = {rr, r2};
            a01 = t01;
            a23 = t01*rr2;
            a45 = a23*rr2;
            a67 = a45*rr2;
            float dtu = dt*uu;
            f2 du2 = {dtu, dtu};
            f2 Bp0 = { bflo(Bv.x), bfhi(Bv.x) }, Bp1 = { bflo(Bv.y), bfhi(Bv.y) };
            f2 Bp2 = { bflo(Bv.z), bfhi(Bv.z) }, Bp3 = { bflo(Bv.w), bfhi(Bv.w) };
            Bq0 = du2*Bp0; Bq1 = du2*Bp1; Bq2 = du2*Bp2; Bq3 = du2*Bp3;
            f2 c0 = { bflo(Cv.x), bfhi(Cv.x) }, c1v = { bflo(Cv.y), bfhi(Cv.y) };
            f2 c2v = { bflo(Cv.z), bfhi(Cv.z) }, c3 = { bflo(Cv.w), bfhi(Cv.w) };
            Cp0 = c0; Cp1 = c1v; Cp2 = c2v; Cp3 = c3;
            ydc = Dd*uu;
        };

        prep(0);

        #pragma unroll 4
        for (int t = 0; t < 384; ++t) {
            int sl = t & 3;
            fetch(sl);

            h0  = __builtin_elementwise_fma(a01, h0,  Bq0);
            h1v = __builtin_elementwise_fma(a23, h1v, Bq1);
            h2v = __builtin_elementwise_fma(a45, h2v, Bq2);
            h3  = __builtin_elementwise_fma(a67, h3,  Bq3);

            f2 yv = Cp0*h0;
            yv = __builtin_elementwise_fma(Cp1, h1v, yv);
            yv = __builtin_elementwise_fma(Cp2, h2v, yv);
            yv = __builtin_elementwise_fma(Cp3, h3,  yv);
            float y = yv.x + yv.y + ydc;

            prep((t+1) & 3);

            *(u16*)(y4b + yo) = f2bf(y);
            yo += (u32)sy;
        }
    } else {
        f2 A2[4];
        #pragma unroll
        for (int j = 0; j < 4; ++j) { A2[j].x = Av[2*j]; A2[j].y = Av[2*j+1]; }
        #pragma unroll 4
        for (int t = 0; t < 384; ++t) {
            int sl = t & 3;
            float uu = bf2f(ub[sl]);
            uint2 dl = dlr[sl];
            uint4 Bv = B4[sl], Cv = C4[sl];
            fetch(sl);

            float z = dbc + dw0*bflo(dl.x) + dw1*bfhi(dl.x)
                          + dw2*bflo(dl.y) + dw3*bfhi(dl.y);
            float dt = softplus_f(z);
            f2 dt2 = {dt, dt};
            f2 e0 = dt2*A2[0], e1 = dt2*A2[1], e2 = dt2*A2[2], e3 = dt2*A2[3];
            f2 a01 = { __expf(e0.x), __expf(e0.y) };
            f2 a23 = { __expf(e1.x), __expf(e1.y) };
            f2 a45 = { __expf(e2.x), __expf(e2.y) };
            f2 a67 = { __expf(e3.x), __expf(e3.y) };

            float dtu = dt*uu;
            f2 du2 = {dtu, dtu};
            f2 Bp0 = { bflo(Bv.x), bfhi(Bv.x) }, Bp1 = { bflo(Bv.y), bfhi(Bv.y) };
            f2 Bp2 = { bflo(Bv.z), bfhi(Bv.z) }, Bp3 = { bflo(Bv.w), bfhi(Bv.w) };
            f2 Cp0 = { bflo(Cv.x), bfhi(Cv.x) }, Cp1 = { bflo(Cv.y), bfhi(Cv.y) };
            f2 Cp2 = { bflo(Cv.z), bfhi(Cv.z) }, Cp3 = { bflo(Cv.w), bfhi(Cv.w) };

            h0  = __builtin_elementwise_fma(a01, h0,  du2*Bp0);
            h1v = __builtin_elementwise_fma(a23, h1v, du2*Bp1);
            h2v = __builtin_elementwise_fma(a45, h2v, du2*Bp2);
            h3  = __builtin_elementwise_fma(a67, h3,  du2*Bp3);

            f2 yv = Cp0*h0;
            yv = __builtin_elementwise_fma(Cp1, h1v, yv);
            yv = __builtin_elementwise_fma(Cp2, h2v, yv);
            yv = __builtin_elementwise_fma(Cp3, h3,  yv);

            float y = yv.x + yv.y + Dd*uu;
            *(u16*)(y4b + yo) = f2bf(y);
            yo += (u32)sy;
        }
    }
}

// ---------------- K5: LN(128) + folded 128->20 + NCHW transpose (pk-FMA) ----------------
__global__ __launch_bounds__(256) void k_merge(
    const u16* __restrict__ y4, const float* __restrict__ Wt,
    const float* __restrict__ rsum, const float* __restrict__ c0,
    float* __restrict__ out)
{
    __shared__ __align__(16) f2 Wt2_s[128*10];   // [k][o2] = {Wt[k][2o2], Wt[k][2o2+1]}
    __shared__ float rs_s[CIN], c0_s[CIN];
    for (int i = threadIdx.x; i < 128*10; i += 256) {
        int k = i / 10, o2 = i % 10;
        Wt2_s[i] = f2{ Wt[k*CIN + 2*o2], Wt[k*CIN + 2*o2 + 1] };
    }
    if (threadIdx.x < CIN) { rs_s[threadIdx.x] = rsum[threadIdx.x]; c0_s[threadIdx.x] = c0[threadIdx.x]; }
    __syncthreads();

    int p = blockIdx.x*256 + threadIdx.x;
    int b = p / HW, rem = p % HW;

    float s1 = 0.f, s2 = 0.f;
    f2 acc2[10];
    #pragma unroll
    for (int o2 = 0; o2 < 10; ++o2) acc2[o2] = f2{0.f, 0.f};

    #pragma unroll 1
    for (int dirk = 0; dirk < 4; ++dirk) {
        const uint4* src = (const uint4*)(y4 + ((size_t)dirk*BHW + p)*32);
        #pragma unroll
        for (int q4 = 0; q4 < 4; ++q4) {
            uint4 v = src[q4];
            u32 w[4] = {v.x, v.y, v.z, v.w};
            #pragma unroll
            for (int i = 0; i < 4; ++i) {
                int k = dirk*32 + q4*8 + i*2;
                float a = bflo(w[i]); float c = bfhi(w[i]);
                s1 += a + c; s2 += a*a + c*c;
                f2 af = {a, a}, cf = {c, c};
                const float4* w0 = (const float4*)&Wt2_s[k*10];
                const float4* w1 = (const float4*)&Wt2_s[(k+1)*10];
                #pragma unroll
                for (int jq = 0; jq < 5; ++jq) {
                    float4 x0 = w0[jq], x1 = w1[jq];
                    acc2[2*jq]   = __builtin_elementwise_fma(f2{x0.x, x0.y}, af, acc2[2*jq]);
                    acc2[2*jq]   = __builtin_elementwise_fma(f2{x1.x, x1.y}, cf, acc2[2*jq]);
                    acc2[2*jq+1] = __builtin_elementwise_fma(f2{x0.z, x0.w}, af, acc2[2*jq+1]);
                    acc2[2*jq+1] = __builtin_elementwise_fma(f2{x1.z, x1.w}, cf, acc2[2*jq+1]);
                }
            }
        }
    }
    float m = s1*(1.f/128.f);
    float var = s2*(1.f/128.f) - m*m;
    float rstd = rsqrtf(var + EPSF);
    #pragma unroll
    for (int o2 = 0; o2 < 10; ++o2) {
        float r0 = rstd*(acc2[o2].x - m*rs_s[2*o2])   + c0_s[2*o2];
        float r1 = rstd*(acc2[o2].y - m*rs_s[2*o2+1]) + c0_s[2*o2+1];
        out[(b*CIN + 2*o2)*HW + rem]   = r0;
        out[(b*CIN + 2*o2+1)*HW + rem] = r1;
    }
}

extern "C" void kernel_launch(void* const* d_in, const int* in_sizes, int n_in,
                              void* d_out, int out_size, void* d_ws, size_t ws_size,
                              hipStream_t stream)
{
    const float* x    = (const float*)d_in[0];
    const float* ng   = (const float*)d_in[1];
    const float* nb   = (const float*)d_in[2];
    const float* ipw  = (const float*)d_in[3];
    const float* cw   = (const float*)d_in[4];
    const float* cb   = (const float*)d_in[5];
    const float* xw   = (const float*)d_in[6];
    const float* dwm  = (const float*)d_in[7];
    const float* dbv  = (const float*)d_in[8];
    const float* Alog = (const float*)d_in[9];
    const float* Dpv  = (const float*)d_in[10];
    const float* mg   = (const float*)d_in[11];
    const float* mb   = (const float*)d_in[12];
    const float* mw   = (const float*)d_in[13];
    const float* ow   = (const float*)d_in[14];
    const float* ob   = (const float*)d_in[15];
    float* out = (float*)d_out;

    const size_t y4_bytes = (size_t)4*BHW*DIN*2;     // 150,994,944 (planar)
    const size_t dl_bytes = (size_t)4*BHW*8;         //  18,874,368
    const size_t bc_bytes = (size_t)4*BHW*32;        //  75,497,472
    const size_t wt_bytes = (size_t)(128*CIN + 64)*4;

    char* ws = (char*)d_ws;
    u16* y4 = (u16*)ws;
    u16* h1 = y4;                                    // alias: h1 dead before y4 written

    size_t dl_pos = y4_bytes + GUARD;
    size_t bc_pos = dl_pos + dl_bytes + GUARD;
    size_t wt_pos = bc_pos + bc_bytes + GUARD;
    size_t need   = wt_pos + wt_bytes + GUARD;       // ~245.6 MB (proven budget; ws < 321MB per R4)

    if (ws_size < need) {
        hipMemsetAsync(d_out, 0x7F, (size_t)out_size*4, stream);  // diagnosable sentinel
        return;
    }

    // h2 (u after conv) lives inside d_out with UGUARD front guard (128K for
    // 4-deep prefetch overrun of the vertical-scan u stream: 4*24576 = 96K).
    char* h2base = (char*)d_out;                     // data at +UGUARD
    u16*  h2 = (u16*)(h2base + UGUARD);              // 128K + 37.75MB + 9.3MB tail < 47.19 MB

    u16* dlA = (u16*)(ws + dl_pos);
    u16* bcA = (u16*)(ws + bc_pos);
    float* Wt   = (float*)(ws + wt_pos);
    float* rsum = Wt + 128*CIN;
    float* c0   = rsum + 32;

    k_prep  <<<1, 128, 0, stream>>>(ow, mw, mg, mb, ob, Wt, rsum, c0);
    k_lnproj<<<BHW/256, 256, 0, stream>>>(x, ng, nb, ipw, h1);
    k_conv  <<<BHW*4/256, 256, 0, stream>>>(h1, cw, cb, h2);
    k_proj  <<<BHW/256, 256, 0, stream>>>(h2, xw, dlA, bcA);
    k_scan  <<<768, 256, 0, stream>>>(
        h2base, (const char*)(ws + dl_pos - GUARD), (const char*)(ws + bc_pos - GUARD),
        Alog, Dpv, dwm, dbv, (char*)y4);
    k_merge <<<BHW/256, 256, 0, stream>>>(y4, Wt, rsum, c0, out);
}